// Round 19
// baseline (420.077 us; speedup 1.0000x reference)
//
#include <hip/hip_runtime.h>

// MoE top-2 of 8 experts. T=4096, H=1024, F=4096.
// memset(ctrl) -> router -> prep(W -> tiled bf16 B-images) -> scan -> assign ->
// gcopy -> GEMM1(relu) -> GEMM2 -> combine.
// Weight layout: per (e,kt,bx) a contiguous 16KB tile holding the EXACT LDS
// image GEMM stages (unit u = n*8 + (koct ^ (n&7))).  Transpose writes 8KB
// sequential bursts; GEMM B staging is a linear copy (no swizzle, no stride
// mul).  GEMM core parked (r13 structure, ~115us each).
#define T_TOK 4096
#define H_DIM 1024
#define F_DIM 4096
#define E_NUM 8
#define R_TOT 8192
#define NT_MAX 72
#define R_CAP (NT_MAX * 128)   // 9216 rows

typedef short bf16x8 __attribute__((ext_vector_type(8)));
typedef float f32x4 __attribute__((ext_vector_type(4)));

__device__ inline unsigned int f2bf_u(float f) {   // RNE f32 -> bf16 (as u32)
  unsigned int u = __builtin_bit_cast(unsigned int, f);
  return (u + 0x7FFFu + ((u >> 16) & 1u)) >> 16;
}
__device__ inline unsigned short f2bf(float f) { return (unsigned short)f2bf_u(f); }

__device__ inline void async16(const void* g, void* l) {
  __builtin_amdgcn_global_load_lds((const __attribute__((address_space(1))) void*)g,
                                   (__attribute__((address_space(3))) void*)l, 16, 0, 0);
}

// ---------------- router (separate: merged version cost ~50us, r16-r18) -------
__global__ __launch_bounds__(256) void router_k(
    const float* __restrict__ x, const float* __restrict__ Wr,
    const float* __restrict__ br, int* __restrict__ ctrl,
    int* __restrict__ t2i, float* __restrict__ t2w) {
  int lane = threadIdx.x & 63;
  int wid  = threadIdx.x >> 6;
  int t = blockIdx.x * 4 + wid;
  const float* xr = x + (size_t)t * H_DIM;
  double acc[E_NUM];
#pragma unroll
  for (int e = 0; e < E_NUM; e++) acc[e] = 0.0;
  for (int i = lane; i < H_DIM; i += 64) {
    float xv = xr[i];
    const float* wr = Wr + (size_t)i * E_NUM;
    float4 w0 = *(const float4*)wr;
    float4 w1 = *(const float4*)(wr + 4);
    acc[0] += (double)xv * w0.x; acc[1] += (double)xv * w0.y;
    acc[2] += (double)xv * w0.z; acc[3] += (double)xv * w0.w;
    acc[4] += (double)xv * w1.x; acc[5] += (double)xv * w1.y;
    acc[6] += (double)xv * w1.z; acc[7] += (double)xv * w1.w;
  }
#pragma unroll
  for (int e = 0; e < E_NUM; e++) {
    double v = acc[e];
    for (int off = 32; off > 0; off >>= 1) v += __shfl_down(v, off);
    acc[e] = v;
  }
  if (lane == 0) {
    float l[E_NUM];
#pragma unroll
    for (int e = 0; e < E_NUM; e++) l[e] = (float)acc[e] + br[e];
    int ia = 0; float la = l[0];
#pragma unroll
    for (int e = 1; e < E_NUM; e++) if (l[e] > la) { la = l[e]; ia = e; }
    int ib = -1; float lb = -3.4e38f;
#pragma unroll
    for (int e = 0; e < E_NUM; e++) if (e != ia && l[e] > lb) { lb = l[e]; ib = e; }
    float w0 = 1.f / (1.f + __expf(lb - la));
    float w1 = 1.f - w0;
    t2i[2 * t] = ia; t2i[2 * t + 1] = ib;
    t2w[2 * t] = w0; t2w[2 * t + 1] = w1;
    atomicAdd(&ctrl[ia], 1);
    atomicAdd(&ctrl[ib], 1);
  }
}

// ------- prep: W -> tiled bf16 B-image, 64x64 per block ------------------------
// Block covers k rows [kt*64,+64) x n cols [bxp*64,+64) of W^T (n = W col).
// Store pass (r18): pack k-row-pairs as u32 into tile32[32][66] (2-way banks).
// Out pass: column n gets a contiguous 128B span at tile + n_local*128; octet o
// (k = o*8..+8) lands at slot o ^ (n_local&7) (bakes the GEMM LDS swizzle).
__global__ __launch_bounds__(256) void prep_k(
    const float* __restrict__ W1, const float* __restrict__ W2,
    unsigned short* __restrict__ WT1, unsigned short* __restrict__ WT2) {
  int bid = blockIdx.x;
  size_t mat = (size_t)H_DIM * F_DIM;
  const float* in; unsigned short* tb; int C, kt, bxp;
  if (bid < 8192) {            // W1 [H=1024 k][F=4096 n]: NKT=16, NBX=32
    int e = bid >> 10, t = bid & 1023;
    in = W1 + e * mat; C = F_DIM;
    kt = t >> 6; bxp = t & 63;                       // bxp: 64-col tile idx
    tb = WT1 + (((size_t)e * 16 + kt) * 32 + (bxp >> 1)) * 8192;
  } else {                     // W2 [F=4096 k][H=1024 n]: NKT=64, NBX=8
    int b3 = bid - 8192;
    int e = b3 >> 10, t = b3 & 1023;
    in = W2 + e * mat; C = H_DIM;
    kt = t >> 4; bxp = t & 15;
    tb = WT2 + (((size_t)e * 64 + kt) * 8 + (bxp >> 1)) * 8192;
  }
  int r0 = kt * 64, c0 = bxp * 64;
  int nl0 = (bxp & 1) * 64;                          // offset within 128-n tile
  __shared__ unsigned int tile32[32][66];            // u32 = {k even, k odd}
  {
    int rp = threadIdx.x >> 3;          // 0..31 k-row-pair
    int tc = (threadIdx.x & 7) * 8;     // 0..56 col base
    const float* s0 = in + (size_t)(r0 + 2 * rp) * C + c0 + tc;
    const float* s1 = s0 + C;
    float4 a0 = *(const float4*)s0, a1 = *(const float4*)(s0 + 4);
    float4 b0 = *(const float4*)s1, b1 = *(const float4*)(s1 + 4);
    uint4 u0, u1;
    u0.x = f2bf_u(a0.x) | (f2bf_u(b0.x) << 16);
    u0.y = f2bf_u(a0.y) | (f2bf_u(b0.y) << 16);
    u0.z = f2bf_u(a0.z) | (f2bf_u(b0.z) << 16);
    u0.w = f2bf_u(a0.w) | (f2bf_u(b0.w) << 16);
    u1.x = f2bf_u(a1.x) | (f2bf_u(b1.x) << 16);
    u1.y = f2bf_u(a1.y) | (f2bf_u(b1.y) << 16);
    u1.z = f2bf_u(a1.z) | (f2bf_u(b1.z) << 16);
    u1.w = f2bf_u(a1.w) | (f2bf_u(b1.w) << 16);
    *(uint4*)&tile32[rp][tc]     = u0;
    *(uint4*)&tile32[rp][tc + 4] = u1;
  }
  __syncthreads();
  {
    int col = threadIdx.x >> 2;         // 0..63  (n_local = nl0 + col)
    int q   = (threadIdx.x & 3) * 2;    // octet pair base
    unsigned short* ob = tb + (size_t)(nl0 + col) * 64;   // 128B span
#pragma unroll
    for (int w = 0; w < 2; w++) {
      int o = q + w;
      int slot = o ^ (col & 7);         // (nl0&7)==0 -> n&7 == col&7
      uint4 v;
      v.x = tile32[4 * o + 0][col];
      v.y = tile32[4 * o + 1][col];
      v.z = tile32[4 * o + 2][col];
      v.w = tile32[4 * o + 3][col];
      *(uint4*)(ob + slot * 8) = v;
    }
  }
}

// ------- scan (1 wave): 128-aligned offsets + tile table (<=72 tiles) ---------
__global__ void scan_k(int* ctrl) {
  int lane = threadIdx.x;
  int c = (lane < 8) ? ctrl[lane] : 0;
  int tiles = (c + 127) >> 7;
  int x = tiles;
  for (int d = 1; d < 8; d <<= 1) {
    int y = __shfl_up(x, d);
    if (lane >= d) x += y;
  }
  int excl = x - tiles;
  if (lane < 8) {
    ctrl[8 + lane]  = excl * 128;
    ctrl[17 + lane] = excl * 128;
  }
  int tot = __shfl(x, 7);
  if (lane == 0) { ctrl[25] = tot; ctrl[16] = tot * 128; }
  int ex[8], tl[8];
#pragma unroll
  for (int e = 0; e < 8; e++) { ex[e] = __shfl(excl, e); tl[e] = __shfl(tiles, e); }
  for (int i = lane; i < tot; i += 64) {
    int myE = 0;
#pragma unroll
    for (int e = 0; e < 8; e++) if (i >= ex[e] && i < ex[e] + tl[e]) myE = e;
    ctrl[32 + 2 * i] = myE;
    ctrl[33 + 2 * i] = i * 128;
  }
}

// ------- assign: wave-aggregated routing (8 atomics/wave) ---------------------
__global__ __launch_bounds__(256) void assign_k(
    const int* __restrict__ t2i, int* __restrict__ ctrl, int* __restrict__ row_map) {
  int g = blockIdx.x * 256 + threadIdx.x;
  int lane = threadIdx.x & 63;
  int e = t2i[g];
  int row = 0;
#pragma unroll
  for (int ee = 0; ee < E_NUM; ee++) {
    unsigned long long mask = __ballot(e == ee);
    if (e == ee) {
      int leader = __ffsll((long long)mask) - 1;
      int cnt = __popcll(mask);
      int rank = __popcll(mask & ((lane == 63) ? ~0ull >> 1 << 1 >> 1 | ((1ull << 63) - 1) & ((1ull << lane) - 1) : ((1ull << lane) - 1)));
      int base = 0;
      if (lane == leader) base = atomicAdd(&ctrl[17 + ee], cnt);
      base = __shfl(base, leader);
      row = base + rank;
    }
  }
  row_map[g] = row;
}

// ---------------- gcopy: x row -> bf16 row at row_map position ----------------
__global__ __launch_bounds__(128) void gcopy_k(
    const float* __restrict__ x, const int* __restrict__ row_map,
    unsigned short* __restrict__ xg) {
  int bid = blockIdx.x;
  int row = row_map[bid];
  int t = bid >> 1;
  const float* src = x + (size_t)t * H_DIM + threadIdx.x * 8;
  unsigned short* dst = xg + (size_t)row * H_DIM + threadIdx.x * 8;
  float4 v0 = *(const float4*)src;
  float4 v1 = *(const float4*)(src + 4);
  uint4 o;
  o.x = f2bf_u(v0.x) | (f2bf_u(v0.y) << 16);
  o.y = f2bf_u(v0.z) | (f2bf_u(v0.w) << 16);
  o.z = f2bf_u(v1.x) | (f2bf_u(v1.y) << 16);
  o.w = f2bf_u(v1.z) | (f2bf_u(v1.w) << 16);
  *(uint4*)dst = o;
}

// ======= grouped BT GEMM: 128x128 tile, BK=64, 4 waves (2x2), 2 blocks/CU =====
// r13 core (PARKED).  A: xg row-major, pre-swizzled source.  B: tiled image,
// linear copy (tile stride = tstride shorts; image already swizzled).
#define BAR() do { __builtin_amdgcn_sched_barrier(0); \
                   __builtin_amdgcn_s_barrier(); \
                   __builtin_amdgcn_sched_barrier(0); } while (0)

#define STGA(kt, ebase, c) \
  async16(Ae + (size_t)((c) * 32 + srcRow) * Kstr + (kt) + srcK8, \
          lds + (ebase) + (c) * 2048 + tid * 8)

#define STGB(tb, ebase, c) \
  async16(Be + (size_t)(tb) * tstride + (c) * 2048 + tid * 8, \
          lds + (ebase) + (c) * 2048 + tid * 8)

#define LDU(ebase, row, koct) \
  (*(const bf16x8*)(lds + (ebase) + (((row) * 8 + ((koct) ^ ((row) & 7))) * 8)))

template <int MAP, bool RELU, bool OUTF32>
__global__ __launch_bounds__(256, 2) void gemm128_k(
    const int* __restrict__ ctrl, const unsigned short* __restrict__ A,
    const unsigned short* __restrict__ Bw, const float* __restrict__ bias,
    void* __restrict__ Cout, int Kstr, int N, int tstride) {
  __shared__ unsigned short lds[32768];
  const int bid = blockIdx.x;
  int rt, bx;
  if (MAP == 1) {
    int wg = (bid & 7) * 288 + (bid >> 3);
    rt = wg >> 5; bx = wg & 31;
  } else {
    int wg = (bid & 7) * 72 + (bid >> 3);
    rt = wg >> 3; bx = wg & 7;
  }
  if (rt >= ctrl[25]) return;
  const int e    = ctrl[32 + 2 * rt];
  const int row0 = ctrl[33 + 2 * rt];
  const unsigned short* Ae = A + (size_t)row0 * Kstr;
  const unsigned short* Be = Bw + (size_t)e * ((size_t)N * Kstr) + (size_t)bx * 8192;
  const int tid = threadIdx.x, lane = tid & 63;
  const int wid = tid >> 6, wm = wid >> 1, wn = wid & 1;
  const int lr = lane & 15, klane = lane >> 4;
  const int srcRow = tid >> 3;
  const int srcK8  = ((tid & 7) ^ (srcRow & 7)) * 8;
  const int NT = Kstr >> 6;

  f32x4 acc[4][4];
  f32x4 zero4 = {0.f, 0.f, 0.f, 0.f};
#pragma unroll
  for (int m = 0; m < 4; m++)
#pragma unroll
    for (int n = 0; n < 4; n++) acc[m][n] = zero4;

  {
    STGA(0, 0, 0); STGA(0, 0, 1); STGA(0, 0, 2); STGA(0, 0, 3);
    STGB(0, 8192, 0); STGB(0, 8192, 1); STGB(0, 8192, 2); STGB(0, 8192, 3);
    STGA(64, 16384, 0); STGA(64, 16384, 1); STGA(64, 16384, 2); STGA(64, 16384, 3);
    STGB(1, 24576, 0); STGB(1, 24576, 1); STGB(1, 24576, 2); STGB(1, 24576, 3);
    asm volatile("s_waitcnt vmcnt(8)" ::: "memory");
    BAR();
  }

  for (int t = 0; t < NT; t++) {
    const int cur = t & 1;
    const int abase = cur * 16384;
    const int bbase = abase + 8192;
    const int tb2 = min(t + 2, NT - 1);
    const int kt2 = tb2 * 64;
    bf16x8 a[4][2], b[4][2];
#pragma unroll
    for (int m = 0; m < 4; m++) {
      int ar = wm * 64 + m * 16 + lr;
      a[m][0] = LDU(abase, ar, klane);
      a[m][1] = LDU(abase, ar, 4 + klane);
    }
#pragma unroll
    for (int n = 0; n < 4; n++) {
      int br = wn * 64 + n * 16 + lr;
      b[n][0] = LDU(bbase, br, klane);
      b[n][1] = LDU(bbase, br, 4 + klane);
    }
    asm volatile("s_waitcnt lgkmcnt(0)" ::: "memory");
    BAR();
    STGA(kt2, abase, 0); STGA(kt2, abase, 1);
    STGA(kt2, abase, 2); STGA(kt2, abase, 3);
    STGB(tb2, bbase, 0); STGB(tb2, bbase, 1);
    STGB(tb2, bbase, 2); STGB(tb2, bbase, 3);
    __builtin_amdgcn_s_setprio(1);
#pragma unroll
    for (int m = 0; m < 4; m++)
#pragma unroll
      for (int n = 0; n < 4; n++) {
        acc[m][n] = __builtin_amdgcn_mfma_f32_16x16x32_bf16(a[m][0], b[n][0], acc[m][n], 0, 0, 0);
        acc[m][n] = __builtin_amdgcn_mfma_f32_16x16x32_bf16(a[m][1], b[n][1], acc[m][n], 0, 0, 0);
      }
    __builtin_amdgcn_s_setprio(0);
    asm volatile("s_waitcnt vmcnt(8)" ::: "memory");
    BAR();
  }

  const int n0 = bx * 128;
  const float* be = bias + (size_t)e * N;
#pragma unroll
  for (int m = 0; m < 4; m++) {
#pragma unroll
    for (int q2 = 0; q2 < 4; q2++) {
      size_t ro = (size_t)(row0 + wm * 64 + m * 16 + (lane >> 4) * 4 + q2) * N;
#pragma unroll
      for (int n = 0; n < 4; n++) {
        int col = n0 + wn * 64 + n * 16 + lr;
        float v = acc[m][n][q2] + be[col];
        if (RELU) v = fmaxf(v, 0.f);
        if (OUTF32) ((float*)Cout)[ro + col] = v;
        else ((unsigned short*)Cout)[ro + col] = f2bf(v);
      }
    }
  }
}

// ---------------- combine: out[t] = w0*y[r0] + w1*y[r1] ----------------------
__global__ __launch_bounds__(256) void combine_k(
    const float* __restrict__ y, const int* __restrict__ row_map,
    const float* __restrict__ t2w, float* __restrict__ out) {
  int t = blockIdx.x;
  int i = threadIdx.x * 4;
  int r0 = row_map[2 * t], r1 = row_map[2 * t + 1];
  float w0 = t2w[2 * t], w1 = t2w[2 * t + 1];
  float4 a = *(const float4*)(y + (size_t)r0 * H_DIM + i);
  float4 b = *(const float4*)(y + (size_t)r1 * H_DIM + i);
  float4 o;
  o.x = w0 * a.x + w1 * b.x;
  o.y = w0 * a.y + w1 * b.y;
  o.z = w0 * a.z + w1 * b.z;
  o.w = w0 * a.w + w1 * b.w;
  *(float4*)(out + (size_t)t * H_DIM + i) = o;
}

extern "C" void kernel_launch(void* const* d_in, const int* in_sizes, int n_in,
                              void* d_out, int out_size, void* d_ws, size_t ws_size,
                              hipStream_t stream) {
  const float* x  = (const float*)d_in[0];
  const float* Wr = (const float*)d_in[1];
  const float* br = (const float*)d_in[2];
  const float* W1 = (const float*)d_in[3];
  const float* b1 = (const float*)d_in[4];
  const float* W2 = (const float*)d_in[5];
  const float* b2 = (const float*)d_in[6];
  float* out = (float*)d_out;

  char* ws = (char*)d_ws;
  int*   ctrl    = (int*)ws;
  int*   t2i     = (int*)(ws + 4096);
  float* t2w     = (float*)(ws + 4096 + 32768);
  int*   row_map = (int*)(ws + 4096 + 65536);
  size_t off = (size_t)1 << 20;
  unsigned short* WT1 = (unsigned short*)(ws + off); off += (size_t)E_NUM * F_DIM * H_DIM * 2;
  unsigned short* WT2 = (unsigned short*)(ws + off); off += (size_t)E_NUM * H_DIM * F_DIM * 2;
  unsigned short* xg  = (unsigned short*)(ws + off); off += (size_t)R_CAP * H_DIM * 2;
  unsigned short* hb  = (unsigned short*)(ws + off); off += (size_t)R_CAP * F_DIM * 2;
  float*          yb  = (float*)(ws + off);          off += (size_t)R_CAP * H_DIM * 4;

  if (ws_size < off) {
    hipMemsetAsync(d_out, 0, (size_t)out_size * 4, stream);
    return;
  }

  hipMemsetAsync(ctrl, 0, 4096, stream);
  router_k<<<dim3(T_TOK / 4), 256, 0, stream>>>(x, Wr, br, ctrl, t2i, t2w);
  prep_k<<<dim3(16384), 256, 0, stream>>>(W1, W2, WT1, WT2);
  scan_k<<<dim3(1), 64, 0, stream>>>(ctrl);
  assign_k<<<dim3(R_TOT / 256), 256, 0, stream>>>(t2i, ctrl, row_map);
  gcopy_k<<<dim3(R_TOT), 128, 0, stream>>>(x, row_map, xg);
  // GEMM1: hb = relu(xg @ W1 + b1)  [rows x F]; B-tile stride = 32*8192 shorts
  gemm128_k<1, true, false><<<dim3(2304), 256, 0, stream>>>(
      ctrl, xg, WT1, b1, hb, H_DIM, F_DIM, 32 * 8192);
  // GEMM2: yb = hb @ W2 + b2  [rows x H]; B-tile stride = 8*8192 shorts
  gemm128_k<2, false, true><<<dim3(576), 256, 0, stream>>>(
      ctrl, hb, WT2, b2, yb, F_DIM, H_DIM, 8 * 8192);
  combine_k<<<dim3(T_TOK), 256, 0, stream>>>(yb, row_map, t2w, out);
}

// Round 20
// 384.438 us; speedup vs baseline: 1.0927x; 1.0927x over previous
//
#include <hip/hip_runtime.h>

// MoE top-2 of 8 experts. T=4096, H=1024, F=4096.  BEST-KNOWN CONFIG (r17).
// memset(ctrl) -> prep+router merged (router FIRST, hides under transpose) ->
// scan -> assign -> gcopy(2 slots/block) -> GEMM1(relu) -> GEMM2 -> combine.
// GEMM parked (r13 core, ~115us each): LDS-traffic+fence bound; 5 structural
// variants (8ph 256^2, K-split, XCD-pin, supertile, 8ph-quadrant) null/regress.
// prep parked: conflict-fixed transpose; instruction/burst variants null.
#define T_TOK 4096
#define H_DIM 1024
#define F_DIM 4096
#define E_NUM 8
#define R_TOT 8192
#define NT_MAX 72
#define R_CAP (NT_MAX * 128)   // 9216 rows

typedef short bf16x8 __attribute__((ext_vector_type(8)));
typedef float f32x4 __attribute__((ext_vector_type(4)));

__device__ inline unsigned short f2bf(float f) {   // RNE f32 -> bf16
  unsigned int u = __builtin_bit_cast(unsigned int, f);
  return (unsigned short)((u + 0x7FFFu + ((u >> 16) & 1u)) >> 16);
}
__device__ inline unsigned int f2bf_u(float f) {
  unsigned int u = __builtin_bit_cast(unsigned int, f);
  return (u + 0x7FFFu + ((u >> 16) & 1u)) >> 16;
}

__device__ inline void async16(const void* g, void* l) {
  __builtin_amdgcn_global_load_lds((const __attribute__((address_space(1))) void*)g,
                                   (__attribute__((address_space(3))) void*)l, 16, 0, 0);
}

// ------- prep+router merged: bid<1024 router (scheduled FIRST), else transpose.
// Transpose: fp32 tile[64][65]; read pass col=tid>>3, r8=(tid&7)*8 ->
// bank ((l&7)*8+i+(l>>3))%32 = all 32 banks 2-way (free); writes 8 lanes x
// 16B = full 128B line per column.
__global__ __launch_bounds__(256) void prep_router_k(
    const float* __restrict__ W1, const float* __restrict__ W2,
    unsigned short* __restrict__ WT1, unsigned short* __restrict__ WT2,
    const float* __restrict__ x, const float* __restrict__ Wr,
    const float* __restrict__ br, int* __restrict__ ctrl,
    int* __restrict__ t2i, float* __restrict__ t2w) {
  int bid = blockIdx.x;
  if (bid < 1024) {
    // ---------------- router path (first: hides under transpose stream) -----
    int lane = threadIdx.x & 63;
    int wid  = threadIdx.x >> 6;
    int t = bid * 4 + wid;
    const float* xr = x + (size_t)t * H_DIM;
    double acc[E_NUM];
#pragma unroll
    for (int e = 0; e < E_NUM; e++) acc[e] = 0.0;
    for (int i = lane; i < H_DIM; i += 64) {
      float xv = xr[i];
      const float* wr = Wr + (size_t)i * E_NUM;
      float4 w0 = *(const float4*)wr;
      float4 w1 = *(const float4*)(wr + 4);
      acc[0] += (double)xv * w0.x; acc[1] += (double)xv * w0.y;
      acc[2] += (double)xv * w0.z; acc[3] += (double)xv * w0.w;
      acc[4] += (double)xv * w1.x; acc[5] += (double)xv * w1.y;
      acc[6] += (double)xv * w1.z; acc[7] += (double)xv * w1.w;
    }
#pragma unroll
    for (int e = 0; e < E_NUM; e++) {
      double v = acc[e];
      for (int off = 32; off > 0; off >>= 1) v += __shfl_down(v, off);
      acc[e] = v;
    }
    if (lane == 0) {
      float l[E_NUM];
#pragma unroll
      for (int e = 0; e < E_NUM; e++) l[e] = (float)acc[e] + br[e];
      int ia = 0; float la = l[0];
#pragma unroll
      for (int e = 1; e < E_NUM; e++) if (l[e] > la) { la = l[e]; ia = e; }
      int ib = -1; float lb = -3.4e38f;
#pragma unroll
      for (int e = 0; e < E_NUM; e++) if (e != ia && l[e] > lb) { lb = l[e]; ib = e; }
      float w0 = 1.f / (1.f + __expf(lb - la));
      float w1 = 1.f - w0;
      t2i[2 * t] = ia; t2i[2 * t + 1] = ib;
      t2w[2 * t] = w0; t2w[2 * t + 1] = w1;
      atomicAdd(&ctrl[ia], 1);
      atomicAdd(&ctrl[ib], 1);
    }
    return;
  }
  // ---------------- transpose path ----------------
  int b2 = bid - 1024;
  size_t mat = (size_t)H_DIM * F_DIM;
  const float* in; unsigned short* out; int R, C, c0, r0;
  if (b2 < 8192) {
    int e = b2 >> 10, t = b2 & 1023;
    in = W1 + e * mat; out = WT1 + e * mat; R = H_DIM; C = F_DIM;
    c0 = (t & 63) * 64; r0 = (t >> 6) * 64;
  } else {
    int b3 = b2 - 8192;
    int e = b3 >> 10, t = b3 & 1023;
    in = W2 + e * mat; out = WT2 + e * mat; R = F_DIM; C = H_DIM;
    c0 = (t & 15) * 64; r0 = (t >> 4) * 64;
  }
  __shared__ float tile[64][65];
  int tr = threadIdx.x >> 4, tc = (threadIdx.x & 15) * 4;
#pragma unroll
  for (int p = 0; p < 4; p++) {
    int r = tr + p * 16;
    float4 v = *(const float4*)(in + (size_t)(r0 + r) * C + c0 + tc);
    tile[r][tc + 0] = v.x; tile[r][tc + 1] = v.y;
    tile[r][tc + 2] = v.z; tile[r][tc + 3] = v.w;
  }
  __syncthreads();
  int colb = threadIdx.x >> 3;        // 0..31
  int r8   = (threadIdx.x & 7) * 8;   // 0..56: 8 lanes x 16B = 128B per column
#pragma unroll
  for (int p = 0; p < 2; p++) {
    int col = colb + p * 32;
    uint4 o;
    o.x = (unsigned int)f2bf(tile[r8 + 0][col]) | ((unsigned int)f2bf(tile[r8 + 1][col]) << 16);
    o.y = (unsigned int)f2bf(tile[r8 + 2][col]) | ((unsigned int)f2bf(tile[r8 + 3][col]) << 16);
    o.z = (unsigned int)f2bf(tile[r8 + 4][col]) | ((unsigned int)f2bf(tile[r8 + 5][col]) << 16);
    o.w = (unsigned int)f2bf(tile[r8 + 6][col]) | ((unsigned int)f2bf(tile[r8 + 7][col]) << 16);
    *(uint4*)(out + (size_t)(c0 + col) * R + r0 + r8) = o;
  }
}

// ------- scan (1 wave): 128-aligned offsets + tile table (<=72 tiles) ---------
__global__ void scan_k(int* ctrl) {
  int lane = threadIdx.x;
  int c = (lane < 8) ? ctrl[lane] : 0;
  int tiles = (c + 127) >> 7;
  int x = tiles;
  for (int d = 1; d < 8; d <<= 1) {
    int y = __shfl_up(x, d);
    if (lane >= d) x += y;
  }
  int excl = x - tiles;
  if (lane < 8) {
    ctrl[8 + lane]  = excl * 128;
    ctrl[17 + lane] = excl * 128;
  }
  int tot = __shfl(x, 7);
  if (lane == 0) { ctrl[25] = tot; ctrl[16] = tot * 128; }
  int ex[8], tl[8];
#pragma unroll
  for (int e = 0; e < 8; e++) { ex[e] = __shfl(excl, e); tl[e] = __shfl(tiles, e); }
  for (int i = lane; i < tot; i += 64) {
    int myE = 0;
#pragma unroll
    for (int e = 0; e < 8; e++) if (i >= ex[e] && i < ex[e] + tl[e]) myE = e;
    ctrl[32 + 2 * i] = myE;
    ctrl[33 + 2 * i] = i * 128;
  }
}

// ------- assign: wave-aggregated routing (8 atomics/wave) ---------------------
__global__ __launch_bounds__(256) void assign_k(
    const int* __restrict__ t2i, int* __restrict__ ctrl, int* __restrict__ row_map) {
  int g = blockIdx.x * 256 + threadIdx.x;
  int lane = threadIdx.x & 63;
  int e = t2i[g];
  int row = 0;
#pragma unroll
  for (int ee = 0; ee < E_NUM; ee++) {
    unsigned long long mask = __ballot(e == ee);
    if (e == ee) {
      int leader = __ffsll((long long)mask) - 1;
      int cnt = __popcll(mask);
      int rank = __popcll(mask & ((lane == 63) ? ~0ull >> 1 << 1 >> 1 | ((1ull << 63) - 1) & ((1ull << lane) - 1) : ((1ull << lane) - 1)));
      int base = 0;
      if (lane == leader) base = atomicAdd(&ctrl[17 + ee], cnt);
      base = __shfl(base, leader);
      row = base + rank;
    }
  }
  row_map[g] = row;
}

// ---- gcopy: x row -> bf16 row at row_map; 256 threads = 2 slots per block ----
__global__ __launch_bounds__(256) void gcopy_k(
    const float* __restrict__ x, const int* __restrict__ row_map,
    unsigned short* __restrict__ xg) {
  int slot = blockIdx.x * 2 + (threadIdx.x >> 7);   // token*2+s
  int tl = threadIdx.x & 127;
  int row = row_map[slot];
  int t = slot >> 1;
  const float* src = x + (size_t)t * H_DIM + tl * 8;
  unsigned short* dst = xg + (size_t)row * H_DIM + tl * 8;
  float4 v0 = *(const float4*)src;
  float4 v1 = *(const float4*)(src + 4);
  uint4 o;
  o.x = f2bf_u(v0.x) | (f2bf_u(v0.y) << 16);
  o.y = f2bf_u(v0.z) | (f2bf_u(v0.w) << 16);
  o.z = f2bf_u(v1.x) | (f2bf_u(v1.y) << 16);
  o.w = f2bf_u(v1.z) | (f2bf_u(v1.w) << 16);
  *(uint4*)dst = o;
}

// ======= grouped BT GEMM: 128x128 tile, BK=64, 4 waves (2x2), 2 blocks/CU =====
// r13-proven (~115us) — PARKED.
#define BAR() do { __builtin_amdgcn_sched_barrier(0); \
                   __builtin_amdgcn_s_barrier(); \
                   __builtin_amdgcn_sched_barrier(0); } while (0)

#define STG(gbase, kt, ebase, c) \
  async16((gbase) + (size_t)((c) * 32 + srcRow) * Kstr + (kt) + srcK8, \
          lds + (ebase) + (c) * 2048 + tid * 8)

#define LDU(ebase, row, koct) \
  (*(const bf16x8*)(lds + (ebase) + (((row) * 8 + ((koct) ^ ((row) & 7))) * 8)))

template <int MAP, bool RELU, bool OUTF32>
__global__ __launch_bounds__(256, 2) void gemm128_k(
    const int* __restrict__ ctrl, const unsigned short* __restrict__ A,
    const unsigned short* __restrict__ Bw, const float* __restrict__ bias,
    void* __restrict__ Cout, int Kstr, int N) {
  __shared__ unsigned short lds[32768];
  const int bid = blockIdx.x;
  int rt, bx;
  if (MAP == 1) {
    int wg = (bid & 7) * 288 + (bid >> 3);
    rt = wg >> 5; bx = wg & 31;
  } else {
    int wg = (bid & 7) * 72 + (bid >> 3);
    rt = wg >> 3; bx = wg & 7;
  }
  if (rt >= ctrl[25]) return;
  const int e    = ctrl[32 + 2 * rt];
  const int row0 = ctrl[33 + 2 * rt];
  const unsigned short* Ae = A + (size_t)row0 * Kstr;
  const unsigned short* Be = Bw + (size_t)e * ((size_t)N * Kstr) + (size_t)bx * 128 * Kstr;
  const int tid = threadIdx.x, lane = tid & 63;
  const int wid = tid >> 6, wm = wid >> 1, wn = wid & 1;
  const int lr = lane & 15, klane = lane >> 4;
  const int srcRow = tid >> 3;
  const int srcK8  = ((tid & 7) ^ (srcRow & 7)) * 8;
  const int NT = Kstr >> 6;

  f32x4 acc[4][4];
  f32x4 zero4 = {0.f, 0.f, 0.f, 0.f};
#pragma unroll
  for (int m = 0; m < 4; m++)
#pragma unroll
    for (int n = 0; n < 4; n++) acc[m][n] = zero4;

  {
    STG(Ae, 0, 0, 0); STG(Ae, 0, 0, 1); STG(Ae, 0, 0, 2); STG(Ae, 0, 0, 3);
    STG(Be, 0, 8192, 0); STG(Be, 0, 8192, 1); STG(Be, 0, 8192, 2); STG(Be, 0, 8192, 3);
    STG(Ae, 64, 16384, 0); STG(Ae, 64, 16384, 1); STG(Ae, 64, 16384, 2); STG(Ae, 64, 16384, 3);
    STG(Be, 64, 24576, 0); STG(Be, 64, 24576, 1); STG(Be, 64, 24576, 2); STG(Be, 64, 24576, 3);
    asm volatile("s_waitcnt vmcnt(8)" ::: "memory");
    BAR();
  }

  for (int t = 0; t < NT; t++) {
    const int cur = t & 1;
    const int abase = cur * 16384;
    const int bbase = abase + 8192;
    const int kt2 = min(t + 2, NT - 1) * 64;
    bf16x8 a[4][2], b[4][2];
#pragma unroll
    for (int m = 0; m < 4; m++) {
      int ar = wm * 64 + m * 16 + lr;
      a[m][0] = LDU(abase, ar, klane);
      a[m][1] = LDU(abase, ar, 4 + klane);
    }
#pragma unroll
    for (int n = 0; n < 4; n++) {
      int br = wn * 64 + n * 16 + lr;
      b[n][0] = LDU(bbase, br, klane);
      b[n][1] = LDU(bbase, br, 4 + klane);
    }
    asm volatile("s_waitcnt lgkmcnt(0)" ::: "memory");
    BAR();
    STG(Ae, kt2, abase, 0); STG(Ae, kt2, abase, 1);
    STG(Ae, kt2, abase, 2); STG(Ae, kt2, abase, 3);
    STG(Be, kt2, bbase, 0); STG(Be, kt2, bbase, 1);
    STG(Be, kt2, bbase, 2); STG(Be, kt2, bbase, 3);
    __builtin_amdgcn_s_setprio(1);
#pragma unroll
    for (int m = 0; m < 4; m++)
#pragma unroll
      for (int n = 0; n < 4; n++) {
        acc[m][n] = __builtin_amdgcn_mfma_f32_16x16x32_bf16(a[m][0], b[n][0], acc[m][n], 0, 0, 0);
        acc[m][n] = __builtin_amdgcn_mfma_f32_16x16x32_bf16(a[m][1], b[n][1], acc[m][n], 0, 0, 0);
      }
    __builtin_amdgcn_s_setprio(0);
    asm volatile("s_waitcnt vmcnt(8)" ::: "memory");
    BAR();
  }

  const int n0 = bx * 128;
  const float* be = bias + (size_t)e * N;
#pragma unroll
  for (int m = 0; m < 4; m++) {
#pragma unroll
    for (int q2 = 0; q2 < 4; q2++) {
      size_t ro = (size_t)(row0 + wm * 64 + m * 16 + (lane >> 4) * 4 + q2) * N;
#pragma unroll
      for (int n = 0; n < 4; n++) {
        int col = n0 + wn * 64 + n * 16 + lr;
        float v = acc[m][n][q2] + be[col];
        if (RELU) v = fmaxf(v, 0.f);
        if (OUTF32) ((float*)Cout)[ro + col] = v;
        else ((unsigned short*)Cout)[ro + col] = f2bf(v);
      }
    }
  }
}

// ---------------- combine: out[t] = w0*y[r0] + w1*y[r1] ----------------------
__global__ __launch_bounds__(256) void combine_k(
    const float* __restrict__ y, const int* __restrict__ row_map,
    const float* __restrict__ t2w, float* __restrict__ out) {
  int t = blockIdx.x;
  int i = threadIdx.x * 4;
  int r0 = row_map[2 * t], r1 = row_map[2 * t + 1];
  float w0 = t2w[2 * t], w1 = t2w[2 * t + 1];
  float4 a = *(const float4*)(y + (size_t)r0 * H_DIM + i);
  float4 b = *(const float4*)(y + (size_t)r1 * H_DIM + i);
  float4 o;
  o.x = w0 * a.x + w1 * b.x;
  o.y = w0 * a.y + w1 * b.y;
  o.z = w0 * a.z + w1 * b.z;
  o.w = w0 * a.w + w1 * b.w;
  *(float4*)(out + (size_t)t * H_DIM + i) = o;
}

extern "C" void kernel_launch(void* const* d_in, const int* in_sizes, int n_in,
                              void* d_out, int out_size, void* d_ws, size_t ws_size,
                              hipStream_t stream) {
  const float* x  = (const float*)d_in[0];
  const float* Wr = (const float*)d_in[1];
  const float* br = (const float*)d_in[2];
  const float* W1 = (const float*)d_in[3];
  const float* b1 = (const float*)d_in[4];
  const float* W2 = (const float*)d_in[5];
  const float* b2 = (const float*)d_in[6];
  float* out = (float*)d_out;

  char* ws = (char*)d_ws;
  int*   ctrl    = (int*)ws;
  int*   t2i     = (int*)(ws + 4096);
  float* t2w     = (float*)(ws + 4096 + 32768);
  int*   row_map = (int*)(ws + 4096 + 65536);
  size_t off = (size_t)1 << 20;
  unsigned short* WT1 = (unsigned short*)(ws + off); off += (size_t)E_NUM * F_DIM * H_DIM * 2;
  unsigned short* WT2 = (unsigned short*)(ws + off); off += (size_t)E_NUM * H_DIM * F_DIM * 2;
  unsigned short* xg  = (unsigned short*)(ws + off); off += (size_t)R_CAP * H_DIM * 2;
  unsigned short* hb  = (unsigned short*)(ws + off); off += (size_t)R_CAP * F_DIM * 2;
  float*          yb  = (float*)(ws + off);          off += (size_t)R_CAP * H_DIM * 4;

  if (ws_size < off) {
    hipMemsetAsync(d_out, 0, (size_t)out_size * 4, stream);
    return;
  }

  hipMemsetAsync(ctrl, 0, 4096, stream);   // before merged kernel: router atomics
  // merged: router (1024 blocks, FIRST) || W transpose/cvt (16384 blocks)
  prep_router_k<<<dim3(17408), 256, 0, stream>>>(
      W1, W2, WT1, WT2, x, Wr, br, ctrl, t2i, t2w);
  scan_k<<<dim3(1), 64, 0, stream>>>(ctrl);
  assign_k<<<dim3(R_TOT / 256), 256, 0, stream>>>(t2i, ctrl, row_map);
  gcopy_k<<<dim3(R_TOT / 2), 256, 0, stream>>>(x, row_map, xg);
  gemm128_k<1, true, false><<<dim3(2304), 256, 0, stream>>>(
      ctrl, xg, WT1, b1, hb, H_DIM, F_DIM);
  gemm128_k<2, false, true><<<dim3(576), 256, 0, stream>>>(
      ctrl, hb, WT2, b2, yb, F_DIM, H_DIM);
  combine_k<<<dim3(T_TOK), 256, 0, stream>>>(yb, row_map, t2w, out);
}

// Round 22
// 376.505 us; speedup vs baseline: 1.1157x; 1.0211x over previous
//
#include <hip/hip_runtime.h>

// MoE top-2 of 8 experts. T=4096, H=1024, F=4096.
// memset(ctrl) -> prep+router merged (router FIRST; NT-stream transpose) ->
// scan -> assign -> gcopy(2 slots/block) -> GEMM1(relu,bf16) ->
// GEMM2(bf16 out) -> combine(bf16 in, NT out).
// GEMM parked (r13 core, ~113us each).  r21 fix: NT builtins need Clang
// ext_vector types, not HIP_vector_type structs.
#define T_TOK 4096
#define H_DIM 1024
#define F_DIM 4096
#define E_NUM 8
#define R_TOT 8192
#define NT_MAX 72
#define R_CAP (NT_MAX * 128)   // 9216 rows

typedef short bf16x8 __attribute__((ext_vector_type(8)));
typedef float f32x4 __attribute__((ext_vector_type(4)));
typedef unsigned int u32x4 __attribute__((ext_vector_type(4)));

__device__ inline unsigned short f2bf(float f) {   // RNE f32 -> bf16
  unsigned int u = __builtin_bit_cast(unsigned int, f);
  return (unsigned short)((u + 0x7FFFu + ((u >> 16) & 1u)) >> 16);
}
__device__ inline unsigned int f2bf_u(float f) {
  unsigned int u = __builtin_bit_cast(unsigned int, f);
  return (u + 0x7FFFu + ((u >> 16) & 1u)) >> 16;
}
__device__ inline float bf2f(unsigned short s) {
  unsigned int u = (unsigned int)s << 16;
  return __builtin_bit_cast(float, u);
}

__device__ inline void async16(const void* g, void* l) {
  __builtin_amdgcn_global_load_lds((const __attribute__((address_space(1))) void*)g,
                                   (__attribute__((address_space(3))) void*)l, 16, 0, 0);
}

// ------- prep+router merged: bid<1024 router (FIRST), else transpose ----------
// Transpose: fp32 tile[64][65]; 2-way banks both passes; NT loads (read-once
// fp32 W) and NT stores (write-once WT, 8 lanes x 16B = full 128B lines).
__global__ __launch_bounds__(256) void prep_router_k(
    const float* __restrict__ W1, const float* __restrict__ W2,
    unsigned short* __restrict__ WT1, unsigned short* __restrict__ WT2,
    const float* __restrict__ x, const float* __restrict__ Wr,
    const float* __restrict__ br, int* __restrict__ ctrl,
    int* __restrict__ t2i, float* __restrict__ t2w) {
  int bid = blockIdx.x;
  if (bid < 1024) {
    // ---------------- router path ----------------
    int lane = threadIdx.x & 63;
    int wid  = threadIdx.x >> 6;
    int t = bid * 4 + wid;
    const float* xr = x + (size_t)t * H_DIM;
    double acc[E_NUM];
#pragma unroll
    for (int e = 0; e < E_NUM; e++) acc[e] = 0.0;
    for (int i = lane; i < H_DIM; i += 64) {
      float xv = xr[i];
      const float* wr = Wr + (size_t)i * E_NUM;
      float4 w0 = *(const float4*)wr;
      float4 w1 = *(const float4*)(wr + 4);
      acc[0] += (double)xv * w0.x; acc[1] += (double)xv * w0.y;
      acc[2] += (double)xv * w0.z; acc[3] += (double)xv * w0.w;
      acc[4] += (double)xv * w1.x; acc[5] += (double)xv * w1.y;
      acc[6] += (double)xv * w1.z; acc[7] += (double)xv * w1.w;
    }
#pragma unroll
    for (int e = 0; e < E_NUM; e++) {
      double v = acc[e];
      for (int off = 32; off > 0; off >>= 1) v += __shfl_down(v, off);
      acc[e] = v;
    }
    if (lane == 0) {
      float l[E_NUM];
#pragma unroll
      for (int e = 0; e < E_NUM; e++) l[e] = (float)acc[e] + br[e];
      int ia = 0; float la = l[0];
#pragma unroll
      for (int e = 1; e < E_NUM; e++) if (l[e] > la) { la = l[e]; ia = e; }
      int ib = -1; float lb = -3.4e38f;
#pragma unroll
      for (int e = 0; e < E_NUM; e++) if (e != ia && l[e] > lb) { lb = l[e]; ib = e; }
      float w0 = 1.f / (1.f + __expf(lb - la));
      float w1 = 1.f - w0;
      t2i[2 * t] = ia; t2i[2 * t + 1] = ib;
      t2w[2 * t] = w0; t2w[2 * t + 1] = w1;
      atomicAdd(&ctrl[ia], 1);
      atomicAdd(&ctrl[ib], 1);
    }
    return;
  }
  // ---------------- transpose path ----------------
  int b2 = bid - 1024;
  size_t mat = (size_t)H_DIM * F_DIM;
  const float* in; unsigned short* out; int R, C, c0, r0;
  if (b2 < 8192) {
    int e = b2 >> 10, t = b2 & 1023;
    in = W1 + e * mat; out = WT1 + e * mat; R = H_DIM; C = F_DIM;
    c0 = (t & 63) * 64; r0 = (t >> 6) * 64;
  } else {
    int b3 = b2 - 8192;
    int e = b3 >> 10, t = b3 & 1023;
    in = W2 + e * mat; out = WT2 + e * mat; R = F_DIM; C = H_DIM;
    c0 = (t & 15) * 64; r0 = (t >> 4) * 64;
  }
  __shared__ float tile[64][65];
  int tr = threadIdx.x >> 4, tc = (threadIdx.x & 15) * 4;
#pragma unroll
  for (int p = 0; p < 4; p++) {
    int r = tr + p * 16;
    f32x4 v = __builtin_nontemporal_load(
        (const f32x4*)(in + (size_t)(r0 + r) * C + c0 + tc));
    tile[r][tc + 0] = v.x; tile[r][tc + 1] = v.y;
    tile[r][tc + 2] = v.z; tile[r][tc + 3] = v.w;
  }
  __syncthreads();
  int colb = threadIdx.x >> 3;        // 0..31
  int r8   = (threadIdx.x & 7) * 8;   // 0..56: 8 lanes x 16B = full 128B line
#pragma unroll
  for (int p = 0; p < 2; p++) {
    int col = colb + p * 32;
    u32x4 o;
    o.x = f2bf_u(tile[r8 + 0][col]) | (f2bf_u(tile[r8 + 1][col]) << 16);
    o.y = f2bf_u(tile[r8 + 2][col]) | (f2bf_u(tile[r8 + 3][col]) << 16);
    o.z = f2bf_u(tile[r8 + 4][col]) | (f2bf_u(tile[r8 + 5][col]) << 16);
    o.w = f2bf_u(tile[r8 + 6][col]) | (f2bf_u(tile[r8 + 7][col]) << 16);
    __builtin_nontemporal_store(o, (u32x4*)(out + (size_t)(c0 + col) * R + r0 + r8));
  }
}

// ------- scan (1 wave): 128-aligned offsets + tile table (<=72 tiles) ---------
__global__ void scan_k(int* ctrl) {
  int lane = threadIdx.x;
  int c = (lane < 8) ? ctrl[lane] : 0;
  int tiles = (c + 127) >> 7;
  int x = tiles;
  for (int d = 1; d < 8; d <<= 1) {
    int y = __shfl_up(x, d);
    if (lane >= d) x += y;
  }
  int excl = x - tiles;
  if (lane < 8) {
    ctrl[8 + lane]  = excl * 128;
    ctrl[17 + lane] = excl * 128;
  }
  int tot = __shfl(x, 7);
  if (lane == 0) { ctrl[25] = tot; ctrl[16] = tot * 128; }
  int ex[8], tl[8];
#pragma unroll
  for (int e = 0; e < 8; e++) { ex[e] = __shfl(excl, e); tl[e] = __shfl(tiles, e); }
  for (int i = lane; i < tot; i += 64) {
    int myE = 0;
#pragma unroll
    for (int e = 0; e < 8; e++) if (i >= ex[e] && i < ex[e] + tl[e]) myE = e;
    ctrl[32 + 2 * i] = myE;
    ctrl[33 + 2 * i] = i * 128;
  }
}

// ------- assign: wave-aggregated routing (8 atomics/wave) ---------------------
__global__ __launch_bounds__(256) void assign_k(
    const int* __restrict__ t2i, int* __restrict__ ctrl, int* __restrict__ row_map) {
  int g = blockIdx.x * 256 + threadIdx.x;
  int lane = threadIdx.x & 63;
  int e = t2i[g];
  int row = 0;
#pragma unroll
  for (int ee = 0; ee < E_NUM; ee++) {
    unsigned long long mask = __ballot(e == ee);
    if (e == ee) {
      int leader = __ffsll((long long)mask) - 1;
      int cnt = __popcll(mask);
      int rank = __popcll(mask & ((lane == 63) ? ~0ull >> 1 << 1 >> 1 | ((1ull << 63) - 1) & ((1ull << lane) - 1) : ((1ull << lane) - 1)));
      int base = 0;
      if (lane == leader) base = atomicAdd(&ctrl[17 + ee], cnt);
      base = __shfl(base, leader);
      row = base + rank;
    }
  }
  row_map[g] = row;
}

// ---- gcopy: x row -> bf16 row at row_map; 256 threads = 2 slots per block ----
__global__ __launch_bounds__(256) void gcopy_k(
    const float* __restrict__ x, const int* __restrict__ row_map,
    unsigned short* __restrict__ xg) {
  int slot = blockIdx.x * 2 + (threadIdx.x >> 7);
  int tl = threadIdx.x & 127;
  int row = row_map[slot];
  int t = slot >> 1;
  const float* src = x + (size_t)t * H_DIM + tl * 8;
  unsigned short* dst = xg + (size_t)row * H_DIM + tl * 8;
  float4 v0 = *(const float4*)src;
  float4 v1 = *(const float4*)(src + 4);
  uint4 o;
  o.x = f2bf_u(v0.x) | (f2bf_u(v0.y) << 16);
  o.y = f2bf_u(v0.z) | (f2bf_u(v0.w) << 16);
  o.z = f2bf_u(v1.x) | (f2bf_u(v1.y) << 16);
  o.w = f2bf_u(v1.z) | (f2bf_u(v1.w) << 16);
  *(uint4*)dst = o;
}

// ======= grouped BT GEMM: 128x128 tile, BK=64, 4 waves (2x2), 2 blocks/CU =====
// r13-proven (~113us) — PARKED.
#define BAR() do { __builtin_amdgcn_sched_barrier(0); \
                   __builtin_amdgcn_s_barrier(); \
                   __builtin_amdgcn_sched_barrier(0); } while (0)

#define STG(gbase, kt, ebase, c) \
  async16((gbase) + (size_t)((c) * 32 + srcRow) * Kstr + (kt) + srcK8, \
          lds + (ebase) + (c) * 2048 + tid * 8)

#define LDU(ebase, row, koct) \
  (*(const bf16x8*)(lds + (ebase) + (((row) * 8 + ((koct) ^ ((row) & 7))) * 8)))

template <int MAP, bool RELU, bool OUTF32>
__global__ __launch_bounds__(256, 2) void gemm128_k(
    const int* __restrict__ ctrl, const unsigned short* __restrict__ A,
    const unsigned short* __restrict__ Bw, const float* __restrict__ bias,
    void* __restrict__ Cout, int Kstr, int N) {
  __shared__ unsigned short lds[32768];
  const int bid = blockIdx.x;
  int rt, bx;
  if (MAP == 1) {
    int wg = (bid & 7) * 288 + (bid >> 3);
    rt = wg >> 5; bx = wg & 31;
  } else {
    int wg = (bid & 7) * 72 + (bid >> 3);
    rt = wg >> 3; bx = wg & 7;
  }
  if (rt >= ctrl[25]) return;
  const int e    = ctrl[32 + 2 * rt];
  const int row0 = ctrl[33 + 2 * rt];
  const unsigned short* Ae = A + (size_t)row0 * Kstr;
  const unsigned short* Be = Bw + (size_t)e * ((size_t)N * Kstr) + (size_t)bx * 128 * Kstr;
  const int tid = threadIdx.x, lane = tid & 63;
  const int wid = tid >> 6, wm = wid >> 1, wn = wid & 1;
  const int lr = lane & 15, klane = lane >> 4;
  const int srcRow = tid >> 3;
  const int srcK8  = ((tid & 7) ^ (srcRow & 7)) * 8;
  const int NT = Kstr >> 6;

  f32x4 acc[4][4];
  f32x4 zero4 = {0.f, 0.f, 0.f, 0.f};
#pragma unroll
  for (int m = 0; m < 4; m++)
#pragma unroll
    for (int n = 0; n < 4; n++) acc[m][n] = zero4;

  {
    STG(Ae, 0, 0, 0); STG(Ae, 0, 0, 1); STG(Ae, 0, 0, 2); STG(Ae, 0, 0, 3);
    STG(Be, 0, 8192, 0); STG(Be, 0, 8192, 1); STG(Be, 0, 8192, 2); STG(Be, 0, 8192, 3);
    STG(Ae, 64, 16384, 0); STG(Ae, 64, 16384, 1); STG(Ae, 64, 16384, 2); STG(Ae, 64, 16384, 3);
    STG(Be, 64, 24576, 0); STG(Be, 64, 24576, 1); STG(Be, 64, 24576, 2); STG(Be, 64, 24576, 3);
    asm volatile("s_waitcnt vmcnt(8)" ::: "memory");
    BAR();
  }

  for (int t = 0; t < NT; t++) {
    const int cur = t & 1;
    const int abase = cur * 16384;
    const int bbase = abase + 8192;
    const int kt2 = min(t + 2, NT - 1) * 64;
    bf16x8 a[4][2], b[4][2];
#pragma unroll
    for (int m = 0; m < 4; m++) {
      int ar = wm * 64 + m * 16 + lr;
      a[m][0] = LDU(abase, ar, klane);
      a[m][1] = LDU(abase, ar, 4 + klane);
    }
#pragma unroll
    for (int n = 0; n < 4; n++) {
      int br = wn * 64 + n * 16 + lr;
      b[n][0] = LDU(bbase, br, klane);
      b[n][1] = LDU(bbase, br, 4 + klane);
    }
    asm volatile("s_waitcnt lgkmcnt(0)" ::: "memory");
    BAR();
    STG(Ae, kt2, abase, 0); STG(Ae, kt2, abase, 1);
    STG(Ae, kt2, abase, 2); STG(Ae, kt2, abase, 3);
    STG(Be, kt2, bbase, 0); STG(Be, kt2, bbase, 1);
    STG(Be, kt2, bbase, 2); STG(Be, kt2, bbase, 3);
    __builtin_amdgcn_s_setprio(1);
#pragma unroll
    for (int m = 0; m < 4; m++)
#pragma unroll
      for (int n = 0; n < 4; n++) {
        acc[m][n] = __builtin_amdgcn_mfma_f32_16x16x32_bf16(a[m][0], b[n][0], acc[m][n], 0, 0, 0);
        acc[m][n] = __builtin_amdgcn_mfma_f32_16x16x32_bf16(a[m][1], b[n][1], acc[m][n], 0, 0, 0);
      }
    __builtin_amdgcn_s_setprio(0);
    asm volatile("s_waitcnt vmcnt(8)" ::: "memory");
    BAR();
  }

  const int n0 = bx * 128;
  const float* be = bias + (size_t)e * N;
#pragma unroll
  for (int m = 0; m < 4; m++) {
#pragma unroll
    for (int q2 = 0; q2 < 4; q2++) {
      size_t ro = (size_t)(row0 + wm * 64 + m * 16 + (lane >> 4) * 4 + q2) * N;
#pragma unroll
      for (int n = 0; n < 4; n++) {
        int col = n0 + wn * 64 + n * 16 + lr;
        float v = acc[m][n][q2] + be[col];
        if (RELU) v = fmaxf(v, 0.f);
        if (OUTF32) ((float*)Cout)[ro + col] = v;
        else ((unsigned short*)Cout)[ro + col] = f2bf(v);
      }
    }
  }
}

// ------- combine: out[t] = w0*y[r0] + w1*y[r1]  (y is bf16, NT out) -----------
__global__ __launch_bounds__(256) void combine_k(
    const unsigned short* __restrict__ y, const int* __restrict__ row_map,
    const float* __restrict__ t2w, float* __restrict__ out) {
  int t = blockIdx.x;
  int i = threadIdx.x * 4;
  int r0 = row_map[2 * t], r1 = row_map[2 * t + 1];
  float w0 = t2w[2 * t], w1 = t2w[2 * t + 1];
  uint2 ua = *(const uint2*)(y + (size_t)r0 * H_DIM + i);
  uint2 ub = *(const uint2*)(y + (size_t)r1 * H_DIM + i);
  f32x4 o;
  o.x = w0 * bf2f((unsigned short)(ua.x & 0xFFFF)) + w1 * bf2f((unsigned short)(ub.x & 0xFFFF));
  o.y = w0 * bf2f((unsigned short)(ua.x >> 16))    + w1 * bf2f((unsigned short)(ub.x >> 16));
  o.z = w0 * bf2f((unsigned short)(ua.y & 0xFFFF)) + w1 * bf2f((unsigned short)(ub.y & 0xFFFF));
  o.w = w0 * bf2f((unsigned short)(ua.y >> 16))    + w1 * bf2f((unsigned short)(ub.y >> 16));
  __builtin_nontemporal_store(o, (f32x4*)(out + (size_t)t * H_DIM + i));
}

extern "C" void kernel_launch(void* const* d_in, const int* in_sizes, int n_in,
                              void* d_out, int out_size, void* d_ws, size_t ws_size,
                              hipStream_t stream) {
  const float* x  = (const float*)d_in[0];
  const float* Wr = (const float*)d_in[1];
  const float* br = (const float*)d_in[2];
  const float* W1 = (const float*)d_in[3];
  const float* b1 = (const float*)d_in[4];
  const float* W2 = (const float*)d_in[5];
  const float* b2 = (const float*)d_in[6];
  float* out = (float*)d_out;

  char* ws = (char*)d_ws;
  int*   ctrl    = (int*)ws;
  int*   t2i     = (int*)(ws + 4096);
  float* t2w     = (float*)(ws + 4096 + 32768);
  int*   row_map = (int*)(ws + 4096 + 65536);
  size_t off = (size_t)1 << 20;
  unsigned short* WT1 = (unsigned short*)(ws + off); off += (size_t)E_NUM * F_DIM * H_DIM * 2;
  unsigned short* WT2 = (unsigned short*)(ws + off); off += (size_t)E_NUM * H_DIM * F_DIM * 2;
  unsigned short* xg  = (unsigned short*)(ws + off); off += (size_t)R_CAP * H_DIM * 2;
  unsigned short* hb  = (unsigned short*)(ws + off); off += (size_t)R_CAP * F_DIM * 2;
  unsigned short* yb  = (unsigned short*)(ws + off); off += (size_t)R_CAP * H_DIM * 2;

  if (ws_size < off) {
    hipMemsetAsync(d_out, 0, (size_t)out_size * 4, stream);
    return;
  }

  hipMemsetAsync(ctrl, 0, 4096, stream);   // before merged kernel: router atomics
  // merged: router (1024 blocks, FIRST) || W transpose/cvt (16384 blocks)
  prep_router_k<<<dim3(17408), 256, 0, stream>>>(
      W1, W2, WT1, WT2, x, Wr, br, ctrl, t2i, t2w);
  scan_k<<<dim3(1), 64, 0, stream>>>(ctrl);
  assign_k<<<dim3(R_TOT / 256), 256, 0, stream>>>(t2i, ctrl, row_map);
  gcopy_k<<<dim3(R_TOT / 2), 256, 0, stream>>>(x, row_map, xg);
  gemm128_k<1, true, false><<<dim3(2304), 256, 0, stream>>>(
      ctrl, xg, WT1, b1, hb, H_DIM, F_DIM);
  gemm128_k<2, false, false><<<dim3(576), 256, 0, stream>>>(
      ctrl, hb, WT2, b2, yb, F_DIM, H_DIM);
  combine_k<<<dim3(T_TOK), 256, 0, stream>>>(yb, row_map, t2w, out);
}